// Round 6
// baseline (206.608 us; speedup 1.0000x reference)
//
#include <hip/hip_runtime.h>
#include <hip/hip_bf16.h>

// Sizes (fixed by the problem)
#define B_  32
#define TE_ 8192
#define H_  128
#define M_  (B_ * TE_)   // 262144 rows

typedef __bf16 bf16x8 __attribute__((ext_vector_type(8)));
typedef __bf16 bf16x4 __attribute__((ext_vector_type(4)));
typedef float  f32x4  __attribute__((ext_vector_type(4)));

// ws layout (floats): Uh[4096] | Wp(16384 bf16 = 8192 float slots) | Lacc[32] | Cacc[4096]
#define WS_UH    0
#define WS_WP    4096
#define WS_LACC  (4096 + 8192)
#define WS_CACC  (WS_LACC + 32)

// LDS strip buffer: 16 rows x 256 B (bf16 row) + 16 B pad -> 272 B row stride
#define SROW 272

__device__ __forceinline__ float tanh_fast(float x) {
  x = fminf(10.f, fmaxf(-10.f, x));
  float e = __expf(2.f * x);
  return (e - 1.f) * __builtin_amdgcn_rcpf(e + 1.f);
}

// ---------------------------------------------------------------------------
// Kernel 1 (32 blocks): block b computes Uh[b][:] (U staged in LDS, coalesced),
// zeros its slice of Lacc/Cacc, and packs W fragment-group f=b into ws.
// Wp order: element ((f*64+lane)*8+j) = W[sK*32+((lane>>4)&3)*8+j][nt*16+(lane&15)],
// f = nt*4+sK.  Packs from global W.
// ---------------------------------------------------------------------------
__global__ __launch_bounds__(256) void prep_kernel(
    const float* __restrict__ dec, const float* __restrict__ U,
    const float* __restrict__ W, float* __restrict__ ws) {
  __shared__ float ldsU[H_ * H_];   // 64 KB (holds U_a for the Uh dot-product)
  __shared__ float ldsd[H_];
  int b = blockIdx.x, t = threadIdx.x;

  float4* l4 = (float4*)ldsU;
  const float4* g4 = (const float4*)U;
  #pragma unroll
  for (int i = 0; i < 16; ++i) l4[t + 256 * i] = g4[t + 256 * i];
  if (t < 32) ((float4*)ldsd)[t] = ((const float4*)(dec + b * H_))[t];
  __syncthreads();

  if (t < H_) {
    float s = 0.f;
    #pragma unroll
    for (int h = 0; h < H_; ++h) s += ldsd[h] * ldsU[h * H_ + t];
    ws[WS_UH + b * H_ + t] = s;
    ws[WS_CACC + b * H_ + t] = 0.f;
  }
  if (t == 0) ws[WS_LACC + b] = 0.f;

  if (t < 64) {
    int nt = b >> 2, sK = b & 3;
    int kk0 = sK * 32 + ((t >> 4) & 3) * 8;
    int nn = nt * 16 + (t & 15);
    __bf16* Wp = (__bf16*)(ws + WS_WP);
    #pragma unroll
    for (int j = 0; j < 8; ++j)
      Wp[(b * 64 + t) * 8 + j] = (__bf16)W[(kk0 + j) * H_ + nn];
  }
}

// ---------------------------------------------------------------------------
// Kernel 2 (fused): per 256-row block, 4 waves x 4 strips of 16 rows.
// Per strip: lane-contiguous nontemporal float4 loads (addr = base + lane*16,
// fully dense 128B lines) -> cvt bf16 -> LDS scatter (272B row stride,
// conflict-free) -> ds_read_b128 MFMA fragments.
// D = W^T * enc^T: each lane holds its own row's (l15) score components;
// reduce = 2 quad shfl_xor, 1 exp. w = exp(score) safe (|score|<=||V||1~5).
// Accumulate per-batch L and partial context C; atomicAdd at block end.
// ANTI-SPILL (R6): plain __launch_bounds__(256) — no min-occupancy clamp
// (R1 showed VGPR_Count=64 with ~100+ live => scratch spills on the critical
// path, explaining 60 MB WRITE_SIZE and all-idle pipes). Per-piece
// cvt->ds_write->next-load interleave kills the hp[8] staging array.
// ---------------------------------------------------------------------------
__global__ __launch_bounds__(256) void fused_kernel(
    const float* __restrict__ enc, const float* __restrict__ ws_in,
    const float* __restrict__ V, float* __restrict__ wout,
    float* __restrict__ ws) {
  __shared__ uint4 ldsW[2048];      // 32 KB packed W; reused as pcbuf at end
  __shared__ float ldsUV[256];      // u[128] | v[128]
  __shared__ float lsum[4];
  __shared__ __align__(16) unsigned char ldsS[4][16 * SROW];  // 17 KB strips

  int t = threadIdx.x, wave = t >> 6, lane = t & 63;
  int l15 = lane & 15, quad = lane >> 4;
  int blockRow = blockIdx.x << 8;   // 256 rows/block, batch-aligned
  int b = blockRow >> 13;

  // issue strip-0 enc loads FIRST (in flight across the W-LDS fill)
  const char* gbase = (const char*)enc + (size_t)(blockRow + (wave << 4)) * (H_ * 4);
  f32x4 ld[8];
  #pragma unroll
  for (int i = 0; i < 8; ++i)
    ld[i] = __builtin_nontemporal_load((const f32x4*)(gbase + i * 1024 + lane * 16));

  const uint4* wsrc = (const uint4*)(ws_in + WS_WP);
  for (int i = t; i < 2048; i += 256) ldsW[i] = wsrc[i];
  if (t < 128) ldsUV[t] = ws_in[WS_UH + b * H_ + t];
  else ldsUV[t] = V[t - 128];
  __syncthreads();

  float cacc[32];
  #pragma unroll
  for (int k = 0; k < 32; ++k) cacc[k] = 0.f;
  float Lpart = 0.f;

  unsigned char* sb = ldsS[wave];
  int wrhi = lane >> 5, wc = lane & 31;   // write row parity / 8B-chunk

  #pragma unroll
  for (int it = 0; it < 4; ++it) {
    // per piece: cvt (waits its load) -> LDS write -> issue next strip's load
    #pragma unroll
    for (int i = 0; i < 8; ++i) {
      union { bf16x4 h; uint2 u; } cv;
      cv.h[0] = (__bf16)ld[i][0]; cv.h[1] = (__bf16)ld[i][1];
      cv.h[2] = (__bf16)ld[i][2]; cv.h[3] = (__bf16)ld[i][3];
      *(uint2*)(sb + (2 * i + wrhi) * SROW + wc * 8) = cv.u;
      if (it < 3)
        ld[i] = __builtin_nontemporal_load(
            (const f32x4*)(gbase + (it + 1) * 32768 + i * 1024 + lane * 16));
    }

    // read MFMA B-fragments: af[s] = row l15, cols s*32+quad*8..+7 (bf16)
    bf16x8 af[4];
    #pragma unroll
    for (int s = 0; s < 4; ++s)
      af[s] = *(const bf16x8*)(sb + l15 * SROW + s * 64 + quad * 16);

    float p = 0.f;
    #pragma unroll
    for (int nt = 0; nt < 8; ++nt) {
      f32x4 acc = {0.f, 0.f, 0.f, 0.f};
      #pragma unroll
      for (int s = 0; s < 4; ++s) {
        union { uint4 u; bf16x8 v; } bw;
        bw.u = ldsW[(nt * 4 + s) * 64 + lane];
        acc = __builtin_amdgcn_mfma_f32_16x16x32_bf16(bw.v, af[s], acc, 0, 0, 0);
      }
      float4 u4 = ((const float4*)ldsUV)[nt * 4 + quad];
      float4 v4 = ((const float4*)(ldsUV + 128))[nt * 4 + quad];
      p += tanh_fast(acc[0] + u4.x) * v4.x;
      p += tanh_fast(acc[1] + u4.y) * v4.y;
      p += tanh_fast(acc[2] + u4.z) * v4.z;
      p += tanh_fast(acc[3] + u4.w) * v4.w;
    }
    // sum the 4 quads -> full score for row l15 in every lane
    p += __shfl_xor(p, 16, 64);
    p += __shfl_xor(p, 32, 64);
    float w = __expf(p);

    int rowBase = blockRow + ((it * 4 + wave) << 4);
    if (quad == 0) wout[rowBase + l15] = w;   // contiguous 64B line
    Lpart += w;                                // l15 distinct; quads duplicate

    // context: this lane's af row IS row l15 -> weight is w directly
    #pragma unroll
    for (int s = 0; s < 4; ++s)
      #pragma unroll
      for (int j = 0; j < 8; ++j)
        cacc[s * 8 + j] += w * (float)af[s][j];
  }

  // reduce context over the 16 rows (l15 lanes) of each quad
  #pragma unroll
  for (int m = 1; m < 16; m <<= 1) {
    #pragma unroll
    for (int k = 0; k < 32; ++k)
      cacc[k] += __shfl_xor(cacc[k], m, 64);
  }
  // L: reduce over l15 bits (quads hold identical copies)
  Lpart += __shfl_xor(Lpart, 1, 64);
  Lpart += __shfl_xor(Lpart, 2, 64);
  Lpart += __shfl_xor(Lpart, 4, 64);
  Lpart += __shfl_xor(Lpart, 8, 64);

  __syncthreads();                   // all ldsW reads done; reuse as pcbuf
  float* pcbuf = (float*)ldsW;       // [4][128]
  if (l15 == 0) {
    #pragma unroll
    for (int s = 0; s < 4; ++s)
      #pragma unroll
      for (int j = 0; j < 8; ++j)
        pcbuf[wave * H_ + s * 32 + quad * 8 + j] = cacc[s * 8 + j];
  }
  if (lane == 0) lsum[wave] = Lpart;
  __syncthreads();

  if (t < H_) {
    float s = pcbuf[0 * H_ + t] + pcbuf[1 * H_ + t] + pcbuf[2 * H_ + t] + pcbuf[3 * H_ + t];
    atomicAdd(&ws[WS_CACC + b * H_ + t], s);
  }
  if (t == 0)
    atomicAdd(&ws[WS_LACC + b], lsum[0] + lsum[1] + lsum[2] + lsum[3]);
}

// ---------------------------------------------------------------------------
// Kernel 3: normalize. Blocks 0..255: e = w / L (float4). Block 256: c = C / L.
// ---------------------------------------------------------------------------
__global__ __launch_bounds__(256) void finalize_kernel(
    float* __restrict__ e, float* __restrict__ c, const float* __restrict__ ws) {
  int t = threadIdx.x;
  if (blockIdx.x < 256) {
    int i4 = blockIdx.x * 256 + t;     // 65536 float4 total
    int b = i4 >> 11;                  // 2048 float4 per batch
    float inv = 1.f / ws[WS_LACC + b];
    float4 v = ((float4*)e)[i4];
    v.x *= inv; v.y *= inv; v.z *= inv; v.w *= inv;
    ((float4*)e)[i4] = v;
  } else {
    #pragma unroll
    for (int k = 0; k < 16; ++k) {
      int i = k * 256 + t;             // 0..4095
      int b = i >> 7;
      c[i] = ws[WS_CACC + i] / ws[WS_LACC + b];
    }
  }
}

// ---------------------------------------------------------------------------
extern "C" void kernel_launch(void* const* d_in, const int* in_sizes, int n_in,
                              void* d_out, int out_size, void* d_ws, size_t ws_size,
                              hipStream_t stream) {
  const float* enc = (const float*)d_in[0];  // [32, 8192, 128]
  const float* dec = (const float*)d_in[1];  // [32, 1, 128]
  const float* Wa  = (const float*)d_in[2];  // [128, 128]
  const float* Ua  = (const float*)d_in[3];  // [128, 128]
  const float* Va  = (const float*)d_in[4];  // [128, 1]

  float* out   = (float*)d_out;
  float* e_out = out;               // [32][8192]
  float* c_out = out + B_ * TE_;    // [32][128]
  float* ws    = (float*)d_ws;

  prep_kernel<<<B_, 256, 0, stream>>>(dec, Ua, Wa, ws);
  fused_kernel<<<M_ / 256, 256, 0, stream>>>(enc, ws, Va, e_out, ws);
  finalize_kernel<<<257, 256, 0, stream>>>(e_out, c_out, ws);
}